// Round 15
// baseline (85.260 us; speedup 1.0000x reference)
//
#include <hip/hip_runtime.h>
#include <math.h>

#define N_NODE 10
#define N_FEAT 8
#define HID 80
#define IN_DIM 40

typedef __attribute__((ext_vector_type(8))) short bf16x8;
typedef __attribute__((ext_vector_type(4))) float f32x4;
typedef __attribute__((ext_vector_type(4))) unsigned uint4v;

#define NF2   9           // layer-2 fragments kept in LDS (1KB each)
#define TILEB 2560        // 16 rows x 160B
#define PAIRB 5120        // 32 rows: exactly 5 x 1KB full-wave transfers

// Manual RNE fp32->bf16 (pack kernels only; finite inputs).
__device__ __forceinline__ short f2bf(float f) {
    unsigned u = __builtin_bit_cast(unsigned, f);
    u += 0x7fffu + ((u >> 16) & 1u);
    return (short)(u >> 16);
}

// HW packed convert: lo->bits[15:0], hi->bits[31:16], RNE. Register-only asm.
__device__ __forceinline__ unsigned cvtpk(float lo, float hi) {
    unsigned r;
    asm("v_cvt_pk_bf16_f32 %0, %1, %2" : "=v"(r) : "v"(lo), "v"(hi));
    return r;
}

// Compiler-level memory fence (TBAA-proof ordering, zero runtime cost).
__device__ __forceinline__ void memfence_compiler() {
    asm volatile("" ::: "memory");
}

// Async 16B/lane global->LDS; LDS dest = wave-uniform base + lane*16.
__device__ __forceinline__ void gload16(const void* gsrc, void* ldst) {
    __builtin_amdgcn_global_load_lds(
        (const __attribute__((address_space(1))) unsigned*)gsrc,
        (__attribute__((address_space(3))) unsigned*)ldst, 16, 0, 0);
}

// ws layout (floats): [0,3200) W_mid | [3200,3240) b_mid | [3240,...) frags
#define FRAG_OFF 3240

// ---------------------------------------------------------------------------
// Fold GraphConv (fixed circulant adjacency) + W_rel/W_root + decoder into
// W_mid [HID][IN_DIM], b_mid [IN_DIM]:  out = relu(relu(x@W_enc+b_enc)@W_mid+b_mid)
// ---------------------------------------------------------------------------
__global__ void precompute_kernel(const float* __restrict__ W_rel,
                                  const float* __restrict__ b_rel,
                                  const float* __restrict__ W_root,
                                  const float* __restrict__ W_dec,
                                  const float* __restrict__ b_dec,
                                  float* __restrict__ W_mid,
                                  float* __restrict__ b_mid)
{
    const float w = expf(-1.0f / 9.0f);
    const int idx = blockIdx.x * blockDim.x + threadIdx.x;
    const int nthr = gridDim.x * blockDim.x;

    for (int e = idx; e < HID * IN_DIM; e += nthr) {
        const int o  = e % IN_DIM;
        const int sf = e / IN_DIM;
        const int s  = sf / N_FEAT;
        const int f  = sf % N_FEAT;
        const int sp = (s + 1) % N_NODE;
        const int sm = (s + N_NODE - 1) % N_NODE;
        float acc = 0.0f;
        #pragma unroll
        for (int g = 0; g < N_FEAT; ++g) {
            acc = fmaf(W_root[f * N_FEAT + g], W_dec[(s  * N_FEAT + g) * IN_DIM + o], acc);
            acc = fmaf(w * W_rel[f * N_FEAT + g],
                       W_dec[(sp * N_FEAT + g) * IN_DIM + o] +
                       W_dec[(sm * N_FEAT + g) * IN_DIM + o], acc);
        }
        W_mid[e] = acc;
    }

    for (int o = idx; o < IN_DIM; o += nthr) {
        float acc = b_dec[o];
        #pragma unroll
        for (int t = 0; t < N_NODE; ++t)
            #pragma unroll
            for (int g = 0; g < N_FEAT; ++g)
                acc = fmaf(b_rel[g], W_dec[(t * N_FEAT + g) * IN_DIM + o], acc);
        b_mid[o] = acc;
    }
}

// ---------------------------------------------------------------------------
// Pack bf16 weight fragments (biases riding spare k-slots) into ws.
//   Wf1[t][s] lane(m,q) elem e : k=32s+8q+e              -> W_enc[k][16t+m], k==40 -> b_enc
//   Wf2[t][s] lane(m,q) elem e : n=32s+16(e>>2)+4q+(e&3) -> W_mid[n][16t+m], n==80 -> b_mid
// ---------------------------------------------------------------------------
__global__ void pack_frags_kernel(const float* __restrict__ W_enc,
                                  const float* __restrict__ b_enc,
                                  float* __restrict__ ws)
{
    const int lane = threadIdx.x;           // 64 threads
    const int m = lane & 15;
    const int q = lane >> 4;
    const float* W_mid = ws;
    const float* b_mid = ws + HID * IN_DIM;
    unsigned* fb = (unsigned*)(ws + FRAG_OFF);

    #pragma unroll
    for (int t = 0; t < 5; ++t)
        #pragma unroll
        for (int s = 0; s < 2; ++s) {
            short v[8];
            #pragma unroll
            for (int e = 0; e < 8; ++e) {
                const int k = 32 * s + 8 * q + e;
                float f = 0.0f;
                if (k < IN_DIM)       f = W_enc[k * HID + 16 * t + m];
                else if (k == IN_DIM) f = b_enc[16 * t + m];
                v[e] = f2bf(f);
            }
            const int fid = t * 2 + s;
            #pragma unroll
            for (int j = 0; j < 4; ++j)
                fb[fid * 256 + lane * 4 + j] =
                    (unsigned)(unsigned short)v[2 * j] |
                    ((unsigned)(unsigned short)v[2 * j + 1] << 16);
        }

    #pragma unroll
    for (int t = 0; t < 3; ++t) {
        const int o = 16 * t + m;
        #pragma unroll
        for (int s = 0; s < 3; ++s) {
            short v[8];
            #pragma unroll
            for (int e = 0; e < 8; ++e) {
                const int n = 32 * s + 16 * (e >> 2) + 4 * q + (e & 3);
                float f = 0.0f;
                if (o < IN_DIM) {
                    if (n < HID)       f = W_mid[n * IN_DIM + o];
                    else if (n == HID) f = b_mid[o];
                }
                v[e] = f2bf(f);
            }
            const int fid = 10 + t * 3 + s;
            #pragma unroll
            for (int j = 0; j < 4; ++j)
                fb[fid * 256 + lane * 4 + j] =
                    (unsigned)(unsigned short)v[2 * j] |
                    ((unsigned)(unsigned short)v[2 * j + 1] << 16);
        }
    }
}

// ---------------------------------------------------------------------------
// Fused MLP, PAIR-PROCESSING: each wave handles 32 rows (2 tiles) per
// iteration. 5 full-wave 1KB async gload_lds per pair (no masked half-ops),
// Wf2 LDS frags read ONCE per pair and reused for both tiles' MFMAs, two
// independent MFMA/cvt chains per iteration (2x ILP), one counted vmcnt(5)
// wait per pair (older gloads retire, newer stores stay in flight).
// Double-buffered linear x/out strips; Wf1 in registers.
// ---------------------------------------------------------------------------
__global__ __launch_bounds__(256, 3) void fused_mfma_kernel(
    const float* __restrict__ x,
    const float* __restrict__ ws,
    float* __restrict__ out,
    int B, int npairs)
{
    __shared__ uint4v wlds[NF2 * 64];                       // 9216 B (Wf2)
    __shared__ __align__(16) char xstrip[4][2][PAIRB];      // 40960 B

    const int tid  = threadIdx.x;
    const int wave = tid >> 6;
    const int lane = tid & 63;
    const int m = lane & 15;
    const int q = lane >> 4;

    const uint4v* fb = (const uint4v*)(ws + FRAG_OFF);

    // ---- block prologue: stage Wf2 fragments into LDS ----
    for (int i = tid; i < NF2 * 64; i += 256)
        wlds[i] = fb[10 * 64 + i];
    __syncthreads();

    // ---- per-wave prologue: Wf1 fragments into registers ----
    bf16x8 Wf1[5][2];
    #pragma unroll
    for (int t = 0; t < 5; ++t)
        #pragma unroll
        for (int s = 0; s < 2; ++s)
            Wf1[t][s] = __builtin_bit_cast(bf16x8, fb[(t * 2 + s) * 64 + lane]);

    char* bufA = xstrip[wave][0];
    char* bufB = xstrip[wave][1];
    const uint4v* wl = wlds + lane;                         // Wf2 frag j at wl[j*64]
    const char* xptr = (const char*)x;
    char* optr = (char*)out;
    const size_t xbytes = (size_t)B * (IN_DIM * 4);

    const int xrow = 160 * m;                               // row base within a tile

    const int nw = gridDim.x * 4;
    int ip = blockIdx.x * 4 + wave;
    if (ip >= npairs) return;

    // clamp a 16B-chunk source offset into bounds (tail pairs load dup data;
    // stores below are exactly guarded, so garbage compute is never visible)
    #define SRCOFF(O_) (((O_) + 16 <= xbytes) ? (O_) : (xbytes - 16))

    // ---- prologue: async-stage pair `ip` into bufA, full drain once ----
    {
        const size_t pb = (size_t)ip * PAIRB;
        #pragma unroll
        for (int i = 0; i < 5; ++i)
            gload16(xptr + SRCOFF(pb + (size_t)lane * 16 + 1024 * i), bufA + 1024 * i);
    }
    asm volatile("s_waitcnt vmcnt(0)" ::: "memory");
    __builtin_amdgcn_sched_barrier(0);

    char* cb = bufA;
    char* nb = bufB;

    // L1 + repack for one 16-row tile at BASE_ -> P0_,P1_,P2_ (bf16x8)
#define TILE_L1(BASE_, P0_, P1_, P2_)                                          \
    {                                                                          \
        const f32x4 xa = __builtin_bit_cast(f32x4, *(const uint4v*)((BASE_) + xrow + 32 * q));      \
        const f32x4 xb = __builtin_bit_cast(f32x4, *(const uint4v*)((BASE_) + xrow + 32 * q + 16)); \
        uint4v xu0;                                                            \
        xu0.x = cvtpk(xa[0], xa[1]); xu0.y = cvtpk(xa[2], xa[3]);              \
        xu0.z = cvtpk(xb[0], xb[1]); xu0.w = cvtpk(xb[2], xb[3]);              \
        uint4v xu1;                                                            \
        if (q == 0) {                                                          \
            const f32x4 xc = __builtin_bit_cast(f32x4, *(const uint4v*)((BASE_) + xrow + 128));     \
            const f32x4 xd = __builtin_bit_cast(f32x4, *(const uint4v*)((BASE_) + xrow + 144));     \
            xu1.x = cvtpk(xc[0], xc[1]); xu1.y = cvtpk(xc[2], xc[3]);          \
            xu1.z = cvtpk(xd[0], xd[1]); xu1.w = cvtpk(xd[2], xd[3]);          \
        } else {                                                               \
            xu1.x = (q == 1) ? 0x3F80u : 0u;                                   \
            xu1.y = 0u; xu1.z = 0u; xu1.w = 0u;                                \
        }                                                                      \
        const bf16x8 X0 = __builtin_bit_cast(bf16x8, xu0);                     \
        const bf16x8 X1 = __builtin_bit_cast(bf16x8, xu1);                     \
        f32x4 a1[5];                                                           \
        _Pragma("unroll")                                                      \
        for (int t = 0; t < 5; ++t) { a1[t][0]=0.f; a1[t][1]=0.f; a1[t][2]=0.f; a1[t][3]=0.f; } \
        _Pragma("unroll")                                                      \
        for (int t = 0; t < 5; ++t) {                                          \
            a1[t] = __builtin_amdgcn_mfma_f32_16x16x32_bf16(Wf1[t][0], X0, a1[t], 0, 0, 0); \
            a1[t] = __builtin_amdgcn_mfma_f32_16x16x32_bf16(Wf1[t][1], X1, a1[t], 0, 0, 0); \
        }                                                                      \
        float r0_, r1_;                                                        \
        uint4v pu0, pu1, pu2;                                                  \
        r0_ = fmaxf(a1[0][0], 0.f); r1_ = fmaxf(a1[0][1], 0.f); pu0.x = cvtpk(r0_, r1_); \
        r0_ = fmaxf(a1[0][2], 0.f); r1_ = fmaxf(a1[0][3], 0.f); pu0.y = cvtpk(r0_, r1_); \
        r0_ = fmaxf(a1[1][0], 0.f); r1_ = fmaxf(a1[1][1], 0.f); pu0.z = cvtpk(r0_, r1_); \
        r0_ = fmaxf(a1[1][2], 0.f); r1_ = fmaxf(a1[1][3], 0.f); pu0.w = cvtpk(r0_, r1_); \
        r0_ = fmaxf(a1[2][0], 0.f); r1_ = fmaxf(a1[2][1], 0.f); pu1.x = cvtpk(r0_, r1_); \
        r0_ = fmaxf(a1[2][2], 0.f); r1_ = fmaxf(a1[2][3], 0.f); pu1.y = cvtpk(r0_, r1_); \
        r0_ = fmaxf(a1[3][0], 0.f); r1_ = fmaxf(a1[3][1], 0.f); pu1.z = cvtpk(r0_, r1_); \
        r0_ = fmaxf(a1[3][2], 0.f); r1_ = fmaxf(a1[3][3], 0.f); pu1.w = cvtpk(r0_, r1_); \
        r0_ = fmaxf(a1[4][0], 0.f); r1_ = fmaxf(a1[4][1], 0.f); pu2.x = cvtpk(r0_, r1_); \
        r0_ = fmaxf(a1[4][2], 0.f); r1_ = fmaxf(a1[4][3], 0.f); pu2.y = cvtpk(r0_, r1_); \
        pu2.z = (q == 0) ? 0x3F80u : 0u;                                       \
        pu2.w = 0u;                                                            \
        P0_ = __builtin_bit_cast(bf16x8, pu0);                                 \
        P1_ = __builtin_bit_cast(bf16x8, pu1);                                 \
        P2_ = __builtin_bit_cast(bf16x8, pu2);                                 \
    }

    while (true) {
        const int ipn = ip + nw;

        // ---- W: counted wait — this pair's 5 gloads are the oldest
        //      outstanding VMEM; previous pair's stores stay in flight ----
        asm volatile("s_waitcnt vmcnt(5)" ::: "memory");
        __builtin_amdgcn_sched_barrier(0);

        // ---- A: issue async staging of next pair into the other buffer ----
        if (ipn < npairs) {
            const size_t pbn = (size_t)ipn * PAIRB;
            #pragma unroll
            for (int i = 0; i < 5; ++i)
                gload16(xptr + SRCOFF(pbn + (size_t)lane * 16 + 1024 * i), nb + 1024 * i);
        }

        // ---- B: layer 1 + repack for both tiles (independent chains) ----
        bf16x8 P0a, P1a, P2a, P0b, P1b, P2b;
        TILE_L1(cb,         P0a, P1a, P2a);
        TILE_L1(cb + TILEB, P0b, P1b, P2b);

        // ---- layer 2, Wf2 read ONCE and reused for both tiles ----
        f32x4 a2a[3], a2b[3];
        #pragma unroll
        for (int t = 0; t < 3; ++t) {
            a2a[t][0]=0.f; a2a[t][1]=0.f; a2a[t][2]=0.f; a2a[t][3]=0.f;
            a2b[t][0]=0.f; a2b[t][1]=0.f; a2b[t][2]=0.f; a2b[t][3]=0.f;
        }
        #pragma unroll
        for (int t = 0; t < 3; ++t) {
            const bf16x8 w0 = __builtin_bit_cast(bf16x8, wl[(t * 3 + 0) * 64]);
            a2a[t] = __builtin_amdgcn_mfma_f32_16x16x32_bf16(w0, P0a, a2a[t], 0, 0, 0);
            a2b[t] = __builtin_amdgcn_mfma_f32_16x16x32_bf16(w0, P0b, a2b[t], 0, 0, 0);
            const bf16x8 w1 = __builtin_bit_cast(bf16x8, wl[(t * 3 + 1) * 64]);
            a2a[t] = __builtin_amdgcn_mfma_f32_16x16x32_bf16(w1, P1a, a2a[t], 0, 0, 0);
            a2b[t] = __builtin_amdgcn_mfma_f32_16x16x32_bf16(w1, P1b, a2b[t], 0, 0, 0);
            const bf16x8 w2 = __builtin_bit_cast(bf16x8, wl[(t * 3 + 2) * 64]);
            a2a[t] = __builtin_amdgcn_mfma_f32_16x16x32_bf16(w2, P2a, a2a[t], 0, 0, 0);
            a2b[t] = __builtin_amdgcn_mfma_f32_16x16x32_bf16(w2, P2b, a2b[t], 0, 0, 0);
        }
        memfence_compiler();

        // ---- C: relu + scatter both out-tiles into cb (MFMA layout) ----
        #pragma unroll
        for (int t = 0; t < 3; ++t) {
            const int o0 = 16 * t + 4 * q;
            if (o0 < IN_DIM) {
                f32x4 va, vb;
                va[0] = fmaxf(a2a[t][0], 0.f); va[1] = fmaxf(a2a[t][1], 0.f);
                va[2] = fmaxf(a2a[t][2], 0.f); va[3] = fmaxf(a2a[t][3], 0.f);
                vb[0] = fmaxf(a2b[t][0], 0.f); vb[1] = fmaxf(a2b[t][1], 0.f);
                vb[2] = fmaxf(a2b[t][2], 0.f); vb[3] = fmaxf(a2b[t][3], 0.f);
                *(uint4v*)(cb + xrow + 4 * o0)         = __builtin_bit_cast(uint4v, va);
                *(uint4v*)(cb + TILEB + xrow + 4 * o0) = __builtin_bit_cast(uint4v, vb);
            }
        }
        memfence_compiler();

        // ---- D: linear readback + 5 fully coalesced 1KB global stores ----
        {
            const size_t pb = (size_t)ip * PAIRB;
            #pragma unroll
            for (int i = 0; i < 5; ++i) {
                const size_t gb = (size_t)lane * 16 + 1024 * i;
                const uint4v s = *(const uint4v*)(cb + gb);
                if (pb + gb + 16 <= xbytes) *(uint4v*)(optr + pb + gb) = s;
            }
        }
        memfence_compiler();

        if (ipn >= npairs) break;
        { char* tmp = cb; cb = nb; nb = tmp; }
        ip = ipn;
    }
#undef TILE_L1
#undef SRCOFF
}

extern "C" void kernel_launch(void* const* d_in, const int* in_sizes, int n_in,
                              void* d_out, int out_size, void* d_ws, size_t ws_size,
                              hipStream_t stream)
{
    const float* x      = (const float*)d_in[0];
    const float* W_enc  = (const float*)d_in[1];
    const float* b_enc  = (const float*)d_in[2];
    const float* W_rel  = (const float*)d_in[3];
    const float* b_rel  = (const float*)d_in[4];
    const float* W_root = (const float*)d_in[5];
    const float* W_dec  = (const float*)d_in[6];
    const float* b_dec  = (const float*)d_in[7];
    float* out = (float*)d_out;

    const int B = in_sizes[0] / IN_DIM;
    const int npairs = (B + 31) / 32;

    float* ws = (float*)d_ws;
    float* W_mid = ws;                       // [0, 3200)
    float* b_mid = ws + HID * IN_DIM;        // [3200, 3240)

    precompute_kernel<<<13, 256, 0, stream>>>(W_rel, b_rel, W_root, W_dec, b_dec,
                                              W_mid, b_mid);
    pack_frags_kernel<<<1, 64, 0, stream>>>(W_enc, b_enc, ws);

    // Grid 2048: 8192 waves -> exactly 4 pairs/wave at B = 1M.
    const int grid = 2048;
    fused_mfma_kernel<<<grid, 256, 0, stream>>>(x, ws, out, B, npairs);
}

// Round 16
// 67.979 us; speedup vs baseline: 1.2542x; 1.2542x over previous
//
#include <hip/hip_runtime.h>
#include <math.h>

#define N_NODE 10
#define N_FEAT 8
#define HID 80
#define IN_DIM 40

typedef __attribute__((ext_vector_type(8))) short bf16x8;
typedef __attribute__((ext_vector_type(4))) float f32x4;
typedef __attribute__((ext_vector_type(4))) unsigned uint4v;

#define NF2   9           // layer-2 fragments kept in LDS (1KB each)
#define TILEB 2560        // 16 rows x 160B, contiguous in x / out

// Manual RNE fp32->bf16 (setup kernel only; finite inputs).
__device__ __forceinline__ short f2bf(float f) {
    unsigned u = __builtin_bit_cast(unsigned, f);
    u += 0x7fffu + ((u >> 16) & 1u);
    return (short)(u >> 16);
}

// HW packed convert: lo->bits[15:0], hi->bits[31:16], RNE. Register-only asm.
__device__ __forceinline__ unsigned cvtpk(float lo, float hi) {
    unsigned r;
    asm("v_cvt_pk_bf16_f32 %0, %1, %2" : "=v"(r) : "v"(lo), "v"(hi));
    return r;
}

// Compiler-level memory fence (TBAA-proof ordering, zero runtime cost).
__device__ __forceinline__ void memfence_compiler() {
    asm volatile("" ::: "memory");
}

// Async 16B/lane global->LDS; LDS dest = wave-uniform base + lane*16.
__device__ __forceinline__ void gload16(const void* gsrc, void* ldst) {
    __builtin_amdgcn_global_load_lds(
        (const __attribute__((address_space(1))) unsigned*)gsrc,
        (__attribute__((address_space(3))) unsigned*)ldst, 16, 0, 0);
}

// ws layout (floats): [0,...) packed frags only (W_mid now lives in setup LDS)
#define FRAG_OFF 0

// ---------------------------------------------------------------------------
// MERGED setup: (1) fold GraphConv + W_rel/W_root + decoder into
// W_mid [HID][IN_DIM] + b_mid [IN_DIM] **in LDS**; (2) pack all 19 bf16
// MFMA weight fragments (biases riding spare k-slots) into ws.
// One kernel instead of two -> one less launch + serial gap in the graph.
//   Wf1[t][s] lane(m,q) elem e : k=32s+8q+e              -> W_enc[k][16t+m], k==40 -> b_enc
//   Wf2[t][s] lane(m,q) elem e : n=32s+16(e>>2)+4q+(e&3) -> W_mid[n][16t+m], n==80 -> b_mid
// ---------------------------------------------------------------------------
__global__ void setup_kernel(const float* __restrict__ W_enc,
                             const float* __restrict__ b_enc,
                             const float* __restrict__ W_rel,
                             const float* __restrict__ b_rel,
                             const float* __restrict__ W_root,
                             const float* __restrict__ W_dec,
                             const float* __restrict__ b_dec,
                             float* __restrict__ ws)
{
    __shared__ float wmid[HID * IN_DIM];   // 12800 B
    __shared__ float bmid[IN_DIM];

    const int tid = threadIdx.x;           // 256 threads
    const float w = expf(-1.0f / 9.0f);

    for (int e = tid; e < HID * IN_DIM; e += 256) {
        const int o  = e % IN_DIM;
        const int sf = e / IN_DIM;
        const int s  = sf / N_FEAT;
        const int f  = sf % N_FEAT;
        const int sp = (s + 1) % N_NODE;
        const int sm = (s + N_NODE - 1) % N_NODE;
        float acc = 0.0f;
        #pragma unroll
        for (int g = 0; g < N_FEAT; ++g) {
            acc = fmaf(W_root[f * N_FEAT + g], W_dec[(s  * N_FEAT + g) * IN_DIM + o], acc);
            acc = fmaf(w * W_rel[f * N_FEAT + g],
                       W_dec[(sp * N_FEAT + g) * IN_DIM + o] +
                       W_dec[(sm * N_FEAT + g) * IN_DIM + o], acc);
        }
        wmid[e] = acc;
    }
    for (int o = tid; o < IN_DIM; o += 256) {
        float acc = b_dec[o];
        #pragma unroll
        for (int t = 0; t < N_NODE; ++t)
            #pragma unroll
            for (int g = 0; g < N_FEAT; ++g)
                acc = fmaf(b_rel[g], W_dec[(t * N_FEAT + g) * IN_DIM + o], acc);
        bmid[o] = acc;
    }
    __syncthreads();

    if (tid < 64) {
        const int lane = tid;
        const int m = lane & 15;
        const int q = lane >> 4;
        unsigned* fb = (unsigned*)(ws + FRAG_OFF);

        #pragma unroll
        for (int t = 0; t < 5; ++t)
            #pragma unroll
            for (int s = 0; s < 2; ++s) {
                short v[8];
                #pragma unroll
                for (int e = 0; e < 8; ++e) {
                    const int k = 32 * s + 8 * q + e;
                    float f = 0.0f;
                    if (k < IN_DIM)       f = W_enc[k * HID + 16 * t + m];
                    else if (k == IN_DIM) f = b_enc[16 * t + m];
                    v[e] = f2bf(f);
                }
                const int fid = t * 2 + s;
                #pragma unroll
                for (int j = 0; j < 4; ++j)
                    fb[fid * 256 + lane * 4 + j] =
                        (unsigned)(unsigned short)v[2 * j] |
                        ((unsigned)(unsigned short)v[2 * j + 1] << 16);
            }

        #pragma unroll
        for (int t = 0; t < 3; ++t) {
            const int o = 16 * t + m;
            #pragma unroll
            for (int s = 0; s < 3; ++s) {
                short v[8];
                #pragma unroll
                for (int e = 0; e < 8; ++e) {
                    const int n = 32 * s + 16 * (e >> 2) + 4 * q + (e & 3);
                    float f = 0.0f;
                    if (o < IN_DIM) {
                        if (n < HID)       f = wmid[n * IN_DIM + o];
                        else if (n == HID) f = bmid[o];
                    }
                    v[e] = f2bf(f);
                }
                const int fid = 10 + t * 3 + s;
                #pragma unroll
                for (int j = 0; j < 4; ++j)
                    fb[fid * 256 + lane * 4 + j] =
                        (unsigned)(unsigned short)v[2 * j] |
                        ((unsigned)(unsigned short)v[2 * j + 1] << 16);
            }
        }
    }
}

// ---------------------------------------------------------------------------
// Fused MLP (R14 structure, unchanged compute): async direct-to-LDS staging
// (global_load_lds, no VGPR round trip), double-buffered linear x-strips,
// counted vmcnt(3), Wf1 in registers / Wf2 in LDS, fully-coalesced 1KB
// global ops both directions. NEW: out stores are NONTEMPORAL (nt flag) —
// zero-reuse write stream bypasses L2/L3 allocation, preserving L3 for x.
// ---------------------------------------------------------------------------
__global__ __launch_bounds__(256, 8) void fused_mfma_kernel(
    const float* __restrict__ x,
    const float* __restrict__ ws,
    float* __restrict__ out,
    int B, int ntiles)
{
    __shared__ uint4v wlds[NF2 * 64];                       // 9216 B (Wf2)
    __shared__ __align__(16) char xstrip[4][2][TILEB];      // 20480 B

    const int tid  = threadIdx.x;
    const int wave = tid >> 6;
    const int lane = tid & 63;
    const int m = lane & 15;
    const int q = lane >> 4;

    const uint4v* fb = (const uint4v*)(ws + FRAG_OFF);

    // ---- block prologue: stage Wf2 fragments into LDS ----
    for (int i = tid; i < NF2 * 64; i += 256)
        wlds[i] = fb[10 * 64 + i];
    __syncthreads();

    // ---- per-wave prologue: Wf1 fragments into registers (10 x dwordx4) ----
    bf16x8 Wf1[5][2];
    #pragma unroll
    for (int t = 0; t < 5; ++t)
        #pragma unroll
        for (int s = 0; s < 2; ++s)
            Wf1[t][s] = __builtin_bit_cast(bf16x8, fb[(t * 2 + s) * 64 + lane]);

    char* bufA = xstrip[wave][0];
    char* bufB = xstrip[wave][1];
    const uint4v* wl = wlds + lane;                         // Wf2 frag j at wl[j*64]
    const char* xptr = (const char*)x;
    char* optr = (char*)out;
    const size_t xbytes = (size_t)B * (IN_DIM * 4);

    const int gb0 = lane * 16, gb1 = gb0 + 1024, gb2 = gb0 + 2048;
    const bool has2 = (lane < 32);
    const int xrow = 160 * m;                               // row base in strip

    const int nw = gridDim.x * 4;
    int it = blockIdx.x * 4 + wave;
    if (it >= ntiles) return;

    // ---- prologue: async-stage tile `it` into bufA, full drain once ----
    {
        const char* src = xptr + (size_t)it * TILEB;
        gload16(src + gb0, bufA);
        gload16(src + gb1, bufA + 1024);
        if (has2) gload16(src + gb2, bufA + 2048);
    }
    asm volatile("s_waitcnt vmcnt(0)" ::: "memory");
    __builtin_amdgcn_sched_barrier(0);

    char* cb = bufA;        // current tile's buffer
    char* nb = bufB;        // next tile's buffer

    while (true) {
        const int itn = it + nw;

        // ---- W: counted wait — current tile's 3 gloads are the oldest
        //      outstanding VMEM; prior stores (newer) may stay in flight ----
        asm volatile("s_waitcnt vmcnt(3)" ::: "memory");
        __builtin_amdgcn_sched_barrier(0);

        // ---- A: issue async staging of next tile into the other buffer ----
        if (itn < ntiles) {
            const char* src = xptr + (size_t)itn * TILEB;
            gload16(src + gb0, nb);
            gload16(src + gb1, nb + 1024);
            if (has2) gload16(src + gb2, nb + 2048);
        }

        // ---- B: x fragments from cb (row m = bytes 160m..160m+159) ----
        const f32x4 xa = __builtin_bit_cast(f32x4, *(const uint4v*)(cb + xrow + 32 * q));
        const f32x4 xb = __builtin_bit_cast(f32x4, *(const uint4v*)(cb + xrow + 32 * q + 16));
        uint4v xu0;
        xu0.x = cvtpk(xa[0], xa[1]); xu0.y = cvtpk(xa[2], xa[3]);
        xu0.z = cvtpk(xb[0], xb[1]); xu0.w = cvtpk(xb[2], xb[3]);
        uint4v xu1;
        if (q == 0) {
            const f32x4 xc = __builtin_bit_cast(f32x4, *(const uint4v*)(cb + xrow + 128));
            const f32x4 xd = __builtin_bit_cast(f32x4, *(const uint4v*)(cb + xrow + 144));
            xu1.x = cvtpk(xc[0], xc[1]); xu1.y = cvtpk(xc[2], xc[3]);
            xu1.z = cvtpk(xd[0], xd[1]); xu1.w = cvtpk(xd[2], xd[3]);
        } else {
            xu1.x = (q == 1) ? 0x3F80u : 0u;   // 1.0 at bias k-slot 40
            xu1.y = 0u; xu1.z = 0u; xu1.w = 0u;
        }
        const bf16x8 X0 = __builtin_bit_cast(bf16x8, xu0);
        const bf16x8 X1 = __builtin_bit_cast(bf16x8, xu1);

        // layer 1 (swapped, reg weights): lane gets y[m][16t+4q+r]
        f32x4 acc1[5];
        #pragma unroll
        for (int t = 0; t < 5; ++t) { acc1[t][0]=0.f; acc1[t][1]=0.f; acc1[t][2]=0.f; acc1[t][3]=0.f; }
        #pragma unroll
        for (int t = 0; t < 5; ++t) {
            acc1[t] = __builtin_amdgcn_mfma_f32_16x16x32_bf16(Wf1[t][0], X0, acc1[t], 0, 0, 0);
            acc1[t] = __builtin_amdgcn_mfma_f32_16x16x32_bf16(Wf1[t][1], X1, acc1[t], 0, 0, 0);
        }

        // relu + packed repack: layer-2 B-fragment IS acc1 under the k-map
        float r0, r1;
        uint4v pu0, pu1, pu2;
        r0 = fmaxf(acc1[0][0], 0.f); r1 = fmaxf(acc1[0][1], 0.f); pu0.x = cvtpk(r0, r1);
        r0 = fmaxf(acc1[0][2], 0.f); r1 = fmaxf(acc1[0][3], 0.f); pu0.y = cvtpk(r0, r1);
        r0 = fmaxf(acc1[1][0], 0.f); r1 = fmaxf(acc1[1][1], 0.f); pu0.z = cvtpk(r0, r1);
        r0 = fmaxf(acc1[1][2], 0.f); r1 = fmaxf(acc1[1][3], 0.f); pu0.w = cvtpk(r0, r1);
        r0 = fmaxf(acc1[2][0], 0.f); r1 = fmaxf(acc1[2][1], 0.f); pu1.x = cvtpk(r0, r1);
        r0 = fmaxf(acc1[2][2], 0.f); r1 = fmaxf(acc1[2][3], 0.f); pu1.y = cvtpk(r0, r1);
        r0 = fmaxf(acc1[3][0], 0.f); r1 = fmaxf(acc1[3][1], 0.f); pu1.z = cvtpk(r0, r1);
        r0 = fmaxf(acc1[3][2], 0.f); r1 = fmaxf(acc1[3][3], 0.f); pu1.w = cvtpk(r0, r1);
        r0 = fmaxf(acc1[4][0], 0.f); r1 = fmaxf(acc1[4][1], 0.f); pu2.x = cvtpk(r0, r1);
        r0 = fmaxf(acc1[4][2], 0.f); r1 = fmaxf(acc1[4][3], 0.f); pu2.y = cvtpk(r0, r1);
        pu2.z = (q == 0) ? 0x3F80u : 0u;       // 1.0 at bias n-slot 80
        pu2.w = 0u;
        const bf16x8 P0 = __builtin_bit_cast(bf16x8, pu0);
        const bf16x8 P1 = __builtin_bit_cast(bf16x8, pu1);
        const bf16x8 P2 = __builtin_bit_cast(bf16x8, pu2);

        // layer 2 (swapped, LDS weights): lane gets out[m][16t+4q+r]
        f32x4 acc2[3];
        #pragma unroll
        for (int t = 0; t < 3; ++t) { acc2[t][0]=0.f; acc2[t][1]=0.f; acc2[t][2]=0.f; acc2[t][3]=0.f; }
        #pragma unroll
        for (int t = 0; t < 3; ++t) {
            const bf16x8 w0 = __builtin_bit_cast(bf16x8, wl[(t * 3 + 0) * 64]);
            acc2[t] = __builtin_amdgcn_mfma_f32_16x16x32_bf16(w0, P0, acc2[t], 0, 0, 0);
            const bf16x8 w1 = __builtin_bit_cast(bf16x8, wl[(t * 3 + 1) * 64]);
            acc2[t] = __builtin_amdgcn_mfma_f32_16x16x32_bf16(w1, P1, acc2[t], 0, 0, 0);
            const bf16x8 w2 = __builtin_bit_cast(bf16x8, wl[(t * 3 + 2) * 64]);
            acc2[t] = __builtin_amdgcn_mfma_f32_16x16x32_bf16(w2, P2, acc2[t], 0, 0, 0);
        }
        memfence_compiler();

        // ---- C: relu + scatter out-tile into cb (row m, cols 16t+4q..) ----
        #pragma unroll
        for (int t = 0; t < 3; ++t) {
            const int o0 = 16 * t + 4 * q;
            if (o0 < IN_DIM) {
                f32x4 v;
                v[0] = fmaxf(acc2[t][0], 0.f);
                v[1] = fmaxf(acc2[t][1], 0.f);
                v[2] = fmaxf(acc2[t][2], 0.f);
                v[3] = fmaxf(acc2[t][3], 0.f);
                *(uint4v*)(cb + xrow + 4 * o0) = __builtin_bit_cast(uint4v, v);
            }
        }
        memfence_compiler();

        // ---- D: linear readback + coalesced 1KB NONTEMPORAL stores ----
        {
            const size_t ob = (size_t)it * TILEB;
            const uint4v s0 = *(const uint4v*)(cb + gb0);
            const uint4v s1 = *(const uint4v*)(cb + gb1);
            if (ob + gb0 + 16 <= xbytes)
                __builtin_nontemporal_store(s0, (uint4v*)(optr + ob + gb0));
            if (ob + gb1 + 16 <= xbytes)
                __builtin_nontemporal_store(s1, (uint4v*)(optr + ob + gb1));
            if (has2) {
                const uint4v s2 = *(const uint4v*)(cb + gb2);
                if (ob + gb2 + 16 <= xbytes)
                    __builtin_nontemporal_store(s2, (uint4v*)(optr + ob + gb2));
            }
        }
        memfence_compiler();

        if (itn >= ntiles) break;
        { char* tmp = cb; cb = nb; nb = tmp; }
        it = itn;
    }
}

extern "C" void kernel_launch(void* const* d_in, const int* in_sizes, int n_in,
                              void* d_out, int out_size, void* d_ws, size_t ws_size,
                              hipStream_t stream)
{
    const float* x      = (const float*)d_in[0];
    const float* W_enc  = (const float*)d_in[1];
    const float* b_enc  = (const float*)d_in[2];
    const float* W_rel  = (const float*)d_in[3];
    const float* b_rel  = (const float*)d_in[4];
    const float* W_root = (const float*)d_in[5];
    const float* W_dec  = (const float*)d_in[6];
    const float* b_dec  = (const float*)d_in[7];
    float* out = (float*)d_out;

    const int B = in_sizes[0] / IN_DIM;
    const int ntiles = (B + 15) / 16;

    float* ws = (float*)d_ws;

    // One merged setup kernel (W_mid in LDS, frags -> ws): 2 launches total.
    setup_kernel<<<1, 256, 0, stream>>>(W_enc, b_enc, W_rel, b_rel, W_root,
                                        W_dec, b_dec, ws);

    // Grid 2048: nw = 8192 -> exactly 8 tiles/wave at B = 1M (no ragged tail).
    const int grid = 2048;
    fused_mfma_kernel<<<grid, 256, 0, stream>>>(x, ws, out, B, ntiles);
}

// Round 17
// 61.074 us; speedup vs baseline: 1.3960x; 1.1131x over previous
//
#include <hip/hip_runtime.h>
#include <math.h>

#define N_NODE 10
#define N_FEAT 8
#define HID 80
#define IN_DIM 40

typedef __attribute__((ext_vector_type(8))) short bf16x8;
typedef __attribute__((ext_vector_type(4))) float f32x4;
typedef __attribute__((ext_vector_type(4))) unsigned uint4v;

#define NF2   9           // layer-2 fragments kept in LDS (1KB each)
#define TILEB 2560        // 16 rows x 160B, contiguous in x / out

// Manual RNE fp32->bf16 (setup kernel only; finite inputs).
__device__ __forceinline__ short f2bf(float f) {
    unsigned u = __builtin_bit_cast(unsigned, f);
    u += 0x7fffu + ((u >> 16) & 1u);
    return (short)(u >> 16);
}

// HW packed convert: lo->bits[15:0], hi->bits[31:16], RNE. Register-only asm.
__device__ __forceinline__ unsigned cvtpk(float lo, float hi) {
    unsigned r;
    asm("v_cvt_pk_bf16_f32 %0, %1, %2" : "=v"(r) : "v"(lo), "v"(hi));
    return r;
}

// Compiler-level memory fence (TBAA-proof ordering, zero runtime cost).
__device__ __forceinline__ void memfence_compiler() {
    asm volatile("" ::: "memory");
}

// Async 16B/lane global->LDS; LDS dest = wave-uniform base + lane*16.
__device__ __forceinline__ void gload16(const void* gsrc, void* ldst) {
    __builtin_amdgcn_global_load_lds(
        (const __attribute__((address_space(1))) unsigned*)gsrc,
        (__attribute__((address_space(3))) unsigned*)ldst, 16, 0, 0);
}

// ws layout (floats): [0,...) packed frags only
#define FRAG_OFF 0

// ---------------------------------------------------------------------------
// PARALLEL setup: 19 blocks x 64 threads; block fid packs exactly fragment
// fid (1KB). Wf1 blocks gather W_enc/b_enc directly. Wf2 blocks compute ONLY
// the W_mid rows their fragment needs (<=512 elems, redundant per block, into
// LDS scratch; same fmaf order as before -> bit-identical results) and pack.
//   Wf1[t][s] lane(m,q) elem e : k=32s+8q+e              -> W_enc[k][16t+m], k==40 -> b_enc
//   Wf2[t][s] lane(m,q) elem e : n=32s+16(e>>2)+4q+(e&3) -> W_mid[n][16t+m], n==80 -> b_mid
// ---------------------------------------------------------------------------
__global__ void setup_kernel(const float* __restrict__ W_enc,
                             const float* __restrict__ b_enc,
                             const float* __restrict__ W_rel,
                             const float* __restrict__ b_rel,
                             const float* __restrict__ W_root,
                             const float* __restrict__ W_dec,
                             const float* __restrict__ b_dec,
                             float* __restrict__ ws)
{
    const int fid  = blockIdx.x;           // 0..18
    const int lane = threadIdx.x;          // 64 threads
    const int m = lane & 15;
    const int q = lane >> 4;
    unsigned* fb = (unsigned*)(ws + FRAG_OFF);

    if (fid < 10) {
        // ---- layer-1 fragment: direct gather from W_enc / b_enc ----
        const int t = fid >> 1, s = fid & 1;
        short v[8];
        #pragma unroll
        for (int e = 0; e < 8; ++e) {
            const int k = 32 * s + 8 * q + e;
            float f = 0.0f;
            if (k < IN_DIM)       f = W_enc[k * HID + 16 * t + m];
            else if (k == IN_DIM) f = b_enc[16 * t + m];
            v[e] = f2bf(f);
        }
        #pragma unroll
        for (int j = 0; j < 4; ++j)
            fb[fid * 256 + lane * 4 + j] =
                (unsigned)(unsigned short)v[2 * j] |
                ((unsigned)(unsigned short)v[2 * j + 1] << 16);
        return;
    }

    // ---- layer-2 fragment: compute needed W_mid rows, then pack ----
    const int t2 = (fid - 10) / 3;
    const int s  = (fid - 10) % 3;
    const int n0 = 32 * s;                       // first n row needed
    const int ncnt = (s < 2) ? 32 : 16;          // rows needed (s=2: 64..79)
    const int obase = 16 * t2;

    __shared__ float wm[33][16];                 // rows [0,ncnt) + bias row 32
    const float w = expf(-1.0f / 9.0f);

    for (int i = lane; i < ncnt * 16; i += 64) {
        const int nn = i >> 4;
        const int oo = i & 15;
        const int n  = n0 + nn;
        const int o  = obase + oo;
        float acc = 0.0f;
        if (o < IN_DIM) {
            const int sn = n / N_FEAT;
            const int f  = n % N_FEAT;
            const int sp = (sn + 1) % N_NODE;
            const int sm_ = (sn + N_NODE - 1) % N_NODE;
            #pragma unroll
            for (int g = 0; g < N_FEAT; ++g) {
                acc = fmaf(W_root[f * N_FEAT + g], W_dec[(sn * N_FEAT + g) * IN_DIM + o], acc);
                acc = fmaf(w * W_rel[f * N_FEAT + g],
                           W_dec[(sp * N_FEAT + g) * IN_DIM + o] +
                           W_dec[(sm_ * N_FEAT + g) * IN_DIM + o], acc);
            }
        }
        wm[nn][oo] = acc;
    }
    if (s == 2) {
        for (int i = lane; i < 16; i += 64) {
            const int o = obase + i;
            float acc = 0.0f;
            if (o < IN_DIM) {
                acc = b_dec[o];
                #pragma unroll
                for (int t = 0; t < N_NODE; ++t)
                    #pragma unroll
                    for (int g = 0; g < N_FEAT; ++g)
                        acc = fmaf(b_rel[g], W_dec[(t * N_FEAT + g) * IN_DIM + o], acc);
            }
            wm[32][i] = acc;
        }
    }
    __syncthreads();

    short v[8];
    #pragma unroll
    for (int e = 0; e < 8; ++e) {
        const int n = 32 * s + 16 * (e >> 2) + 4 * q + (e & 3);
        float f = 0.0f;
        if (obase + m < IN_DIM) {
            if (n < HID) {
                const int nn = n - n0;           // in [0, ncnt) by construction
                f = wm[nn][m];
            } else if (n == HID) {
                f = wm[32][m];
            }
        }
        v[e] = f2bf(f);
    }
    #pragma unroll
    for (int j = 0; j < 4; ++j)
        fb[fid * 256 + lane * 4 + j] =
            (unsigned)(unsigned short)v[2 * j] |
            ((unsigned)(unsigned short)v[2 * j + 1] << 16);
}

// ---------------------------------------------------------------------------
// Fused MLP (R16, unchanged): async direct-to-LDS staging (global_load_lds,
// no VGPR round trip), double-buffered linear x-strips, counted vmcnt(3),
// Wf1 in registers / Wf2 in LDS, fully-coalesced 1KB global ops both
// directions, NONTEMPORAL out stores (zero-reuse write stream bypasses
// L2/L3 allocation, preserving cache for x).
// ---------------------------------------------------------------------------
__global__ __launch_bounds__(256, 8) void fused_mfma_kernel(
    const float* __restrict__ x,
    const float* __restrict__ ws,
    float* __restrict__ out,
    int B, int ntiles)
{
    __shared__ uint4v wlds[NF2 * 64];                       // 9216 B (Wf2)
    __shared__ __align__(16) char xstrip[4][2][TILEB];      // 20480 B

    const int tid  = threadIdx.x;
    const int wave = tid >> 6;
    const int lane = tid & 63;
    const int m = lane & 15;
    const int q = lane >> 4;

    const uint4v* fb = (const uint4v*)(ws + FRAG_OFF);

    // ---- block prologue: stage Wf2 fragments into LDS ----
    for (int i = tid; i < NF2 * 64; i += 256)
        wlds[i] = fb[10 * 64 + i];
    __syncthreads();

    // ---- per-wave prologue: Wf1 fragments into registers (10 x dwordx4) ----
    bf16x8 Wf1[5][2];
    #pragma unroll
    for (int t = 0; t < 5; ++t)
        #pragma unroll
        for (int s = 0; s < 2; ++s)
            Wf1[t][s] = __builtin_bit_cast(bf16x8, fb[(t * 2 + s) * 64 + lane]);

    char* bufA = xstrip[wave][0];
    char* bufB = xstrip[wave][1];
    const uint4v* wl = wlds + lane;                         // Wf2 frag j at wl[j*64]
    const char* xptr = (const char*)x;
    char* optr = (char*)out;
    const size_t xbytes = (size_t)B * (IN_DIM * 4);

    const int gb0 = lane * 16, gb1 = gb0 + 1024, gb2 = gb0 + 2048;
    const bool has2 = (lane < 32);
    const int xrow = 160 * m;                               // row base in strip

    const int nw = gridDim.x * 4;
    int it = blockIdx.x * 4 + wave;
    if (it >= ntiles) return;

    // ---- prologue: async-stage tile `it` into bufA, full drain once ----
    {
        const char* src = xptr + (size_t)it * TILEB;
        gload16(src + gb0, bufA);
        gload16(src + gb1, bufA + 1024);
        if (has2) gload16(src + gb2, bufA + 2048);
    }
    asm volatile("s_waitcnt vmcnt(0)" ::: "memory");
    __builtin_amdgcn_sched_barrier(0);

    char* cb = bufA;        // current tile's buffer
    char* nb = bufB;        // next tile's buffer

    while (true) {
        const int itn = it + nw;

        // ---- W: counted wait — current tile's 3 gloads are the oldest
        //      outstanding VMEM; prior stores (newer) may stay in flight ----
        asm volatile("s_waitcnt vmcnt(3)" ::: "memory");
        __builtin_amdgcn_sched_barrier(0);

        // ---- A: issue async staging of next tile into the other buffer ----
        if (itn < ntiles) {
            const char* src = xptr + (size_t)itn * TILEB;
            gload16(src + gb0, nb);
            gload16(src + gb1, nb + 1024);
            if (has2) gload16(src + gb2, nb + 2048);
        }

        // ---- B: x fragments from cb (row m = bytes 160m..160m+159) ----
        const f32x4 xa = __builtin_bit_cast(f32x4, *(const uint4v*)(cb + xrow + 32 * q));
        const f32x4 xb = __builtin_bit_cast(f32x4, *(const uint4v*)(cb + xrow + 32 * q + 16));
        uint4v xu0;
        xu0.x = cvtpk(xa[0], xa[1]); xu0.y = cvtpk(xa[2], xa[3]);
        xu0.z = cvtpk(xb[0], xb[1]); xu0.w = cvtpk(xb[2], xb[3]);
        uint4v xu1;
        if (q == 0) {
            const f32x4 xc = __builtin_bit_cast(f32x4, *(const uint4v*)(cb + xrow + 128));
            const f32x4 xd = __builtin_bit_cast(f32x4, *(const uint4v*)(cb + xrow + 144));
            xu1.x = cvtpk(xc[0], xc[1]); xu1.y = cvtpk(xc[2], xc[3]);
            xu1.z = cvtpk(xd[0], xd[1]); xu1.w = cvtpk(xd[2], xd[3]);
        } else {
            xu1.x = (q == 1) ? 0x3F80u : 0u;   // 1.0 at bias k-slot 40
            xu1.y = 0u; xu1.z = 0u; xu1.w = 0u;
        }
        const bf16x8 X0 = __builtin_bit_cast(bf16x8, xu0);
        const bf16x8 X1 = __builtin_bit_cast(bf16x8, xu1);

        // layer 1 (swapped, reg weights): lane gets y[m][16t+4q+r]
        f32x4 acc1[5];
        #pragma unroll
        for (int t = 0; t < 5; ++t) { acc1[t][0]=0.f; acc1[t][1]=0.f; acc1[t][2]=0.f; acc1[t][3]=0.f; }
        #pragma unroll
        for (int t = 0; t < 5; ++t) {
            acc1[t] = __builtin_amdgcn_mfma_f32_16x16x32_bf16(Wf1[t][0], X0, acc1[t], 0, 0, 0);
            acc1[t] = __builtin_amdgcn_mfma_f32_16x16x32_bf16(Wf1[t][1], X1, acc1[t], 0, 0, 0);
        }

        // relu + packed repack: layer-2 B-fragment IS acc1 under the k-map
        float r0, r1;
        uint4v pu0, pu1, pu2;
        r0 = fmaxf(acc1[0][0], 0.f); r1 = fmaxf(acc1[0][1], 0.f); pu0.x = cvtpk(r0, r1);
        r0 = fmaxf(acc1[0][2], 0.f); r1 = fmaxf(acc1[0][3], 0.f); pu0.y = cvtpk(r0, r1);
        r0 = fmaxf(acc1[1][0], 0.f); r1 = fmaxf(acc1[1][1], 0.f); pu0.z = cvtpk(r0, r1);
        r0 = fmaxf(acc1[1][2], 0.f); r1 = fmaxf(acc1[1][3], 0.f); pu0.w = cvtpk(r0, r1);
        r0 = fmaxf(acc1[2][0], 0.f); r1 = fmaxf(acc1[2][1], 0.f); pu1.x = cvtpk(r0, r1);
        r0 = fmaxf(acc1[2][2], 0.f); r1 = fmaxf(acc1[2][3], 0.f); pu1.y = cvtpk(r0, r1);
        r0 = fmaxf(acc1[3][0], 0.f); r1 = fmaxf(acc1[3][1], 0.f); pu1.z = cvtpk(r0, r1);
        r0 = fmaxf(acc1[3][2], 0.f); r1 = fmaxf(acc1[3][3], 0.f); pu1.w = cvtpk(r0, r1);
        r0 = fmaxf(acc1[4][0], 0.f); r1 = fmaxf(acc1[4][1], 0.f); pu2.x = cvtpk(r0, r1);
        r0 = fmaxf(acc1[4][2], 0.f); r1 = fmaxf(acc1[4][3], 0.f); pu2.y = cvtpk(r0, r1);
        pu2.z = (q == 0) ? 0x3F80u : 0u;       // 1.0 at bias n-slot 80
        pu2.w = 0u;
        const bf16x8 P0 = __builtin_bit_cast(bf16x8, pu0);
        const bf16x8 P1 = __builtin_bit_cast(bf16x8, pu1);
        const bf16x8 P2 = __builtin_bit_cast(bf16x8, pu2);

        // layer 2 (swapped, LDS weights): lane gets out[m][16t+4q+r]
        f32x4 acc2[3];
        #pragma unroll
        for (int t = 0; t < 3; ++t) { acc2[t][0]=0.f; acc2[t][1]=0.f; acc2[t][2]=0.f; acc2[t][3]=0.f; }
        #pragma unroll
        for (int t = 0; t < 3; ++t) {
            const bf16x8 w0 = __builtin_bit_cast(bf16x8, wl[(t * 3 + 0) * 64]);
            acc2[t] = __builtin_amdgcn_mfma_f32_16x16x32_bf16(w0, P0, acc2[t], 0, 0, 0);
            const bf16x8 w1 = __builtin_bit_cast(bf16x8, wl[(t * 3 + 1) * 64]);
            acc2[t] = __builtin_amdgcn_mfma_f32_16x16x32_bf16(w1, P1, acc2[t], 0, 0, 0);
            const bf16x8 w2 = __builtin_bit_cast(bf16x8, wl[(t * 3 + 2) * 64]);
            acc2[t] = __builtin_amdgcn_mfma_f32_16x16x32_bf16(w2, P2, acc2[t], 0, 0, 0);
        }
        memfence_compiler();

        // ---- C: relu + scatter out-tile into cb (row m, cols 16t+4q..) ----
        #pragma unroll
        for (int t = 0; t < 3; ++t) {
            const int o0 = 16 * t + 4 * q;
            if (o0 < IN_DIM) {
                f32x4 v;
                v[0] = fmaxf(acc2[t][0], 0.f);
                v[1] = fmaxf(acc2[t][1], 0.f);
                v[2] = fmaxf(acc2[t][2], 0.f);
                v[3] = fmaxf(acc2[t][3], 0.f);
                *(uint4v*)(cb + xrow + 4 * o0) = __builtin_bit_cast(uint4v, v);
            }
        }
        memfence_compiler();

        // ---- D: linear readback + coalesced 1KB NONTEMPORAL stores ----
        {
            const size_t ob = (size_t)it * TILEB;
            const uint4v s0 = *(const uint4v*)(cb + gb0);
            const uint4v s1 = *(const uint4v*)(cb + gb1);
            if (ob + gb0 + 16 <= xbytes)
                __builtin_nontemporal_store(s0, (uint4v*)(optr + ob + gb0));
            if (ob + gb1 + 16 <= xbytes)
                __builtin_nontemporal_store(s1, (uint4v*)(optr + ob + gb1));
            if (has2) {
                const uint4v s2 = *(const uint4v*)(cb + gb2);
                if (ob + gb2 + 16 <= xbytes)
                    __builtin_nontemporal_store(s2, (uint4v*)(optr + ob + gb2));
            }
        }
        memfence_compiler();

        if (itn >= ntiles) break;
        { char* tmp = cb; cb = nb; nb = tmp; }
        it = itn;
    }
}

extern "C" void kernel_launch(void* const* d_in, const int* in_sizes, int n_in,
                              void* d_out, int out_size, void* d_ws, size_t ws_size,
                              hipStream_t stream)
{
    const float* x      = (const float*)d_in[0];
    const float* W_enc  = (const float*)d_in[1];
    const float* b_enc  = (const float*)d_in[2];
    const float* W_rel  = (const float*)d_in[3];
    const float* b_rel  = (const float*)d_in[4];
    const float* W_root = (const float*)d_in[5];
    const float* W_dec  = (const float*)d_in[6];
    const float* b_dec  = (const float*)d_in[7];
    float* out = (float*)d_out;

    const int B = in_sizes[0] / IN_DIM;
    const int ntiles = (B + 15) / 16;

    float* ws = (float*)d_ws;

    // Parallel setup: 19 blocks, one 1KB fragment each (~2-3 us wall).
    setup_kernel<<<19, 64, 0, stream>>>(W_enc, b_enc, W_rel, b_rel, W_root,
                                        W_dec, b_dec, ws);

    // Grid 2048: nw = 8192 -> exactly 8 tiles/wave at B = 1M (no ragged tail).
    const int grid = 2048;
    fused_mfma_kernel<<<grid, 256, 0, stream>>>(x, ws, out, B, ntiles);
}